// Round 7
// baseline (171.203 us; speedup 1.0000x reference)
//
#include <hip/hip_runtime.h>
#include <hip/hip_bf16.h>

// DeepFM on MI355X. B=16384, NF=50, K=16, V=1e6, H=400, d=800.
// index = repeat(arange(B), NF) -> sample s owns rows [s*50, s*50+50).
//
// Timed-region decomposition: ~121us = 3x 256-MiB harness poison fills
// (fixed floor) + prep ~14us + fused (target; R6 ~31us).
//
// R7 structure: barrier-free K-loops.
//   k1 prep:  unchanged (transpose W0->W0t [512][800], W1->W1t [512][416],
//             bf16 n-major zero-padded; gather -> fs + x bf16 [16384][800]).
//   k2 fused: one block / 64-sample panel, 512 threads = 8 waves, 1M x 8N
//             (per-wave tile 64 rows x 64 cols, nbase = wave*64, N=512;
//             cols 448..511 hit zero rows of W0t/W1t -> harmless).
//             - A panel (64x800 bf16 = 100 KB) preloaded to LDS ONCE
//               (chunked per plane, rule-#21 source swizzle); ONE barrier.
//             - B fragments read DIRECTLY global->regs (W0t/W1t are
//               L2-resident; same L2 traffic as staging, no LDS cost,
//               no staging barriers), 2-plane named register dbuf.
//             - phase 1: 25 planes, NO barriers (compiler fine-grained
//               waitcnt does the scheduling -- m97 regime).
//             - h0 -> LDS (overwrites dead A panel), 2 barriers.
//             - phase 2: 13 planes vs W1t, NO barriers.
//             - epilogue: relu(.)+b1 dot W2, cross-wave red, sigmoid.
//             Barriers: 4 total (was ~41). LDS reads: 32 b128/plane/CU
//             (was 72). T5 setprio kept around MFMA clusters.

#define BATCH 16384
#define NFLD  50
#define EK    16
#define DDIM  800   // NF*K (= gemm1 K, 25 planes)
#define HDIM  400
#define HPAD  416   // gemm2 K (13 planes)
#define NPAD  512   // W0t/W1t rows (448..511 are zeros)

#define TB_W0 400            // 25 k-tiles x 16 n-tiles
#define TB_W1 208            // 13 k-tiles x 16 n-tiles
#define TBLK  (TB_W0 + TB_W1)
#define GBLK  (BATCH / 16)

#define MROWS 64             // samples per fused block
#define P1    (DDIM / 32)    // 25
#define P2    (HPAD / 32)    // 13
#define H0S   424            // h0 LDS stride (bf16)

#define REDOFF  102400       // after 100 KB A panel
#define LDSSZ   104448       // + 2 KB red

#define VMCNT(N) asm volatile("s_waitcnt vmcnt(" #N ")" ::: "memory")

typedef __attribute__((ext_vector_type(8))) __bf16 bf16x8;
typedef __attribute__((ext_vector_type(4))) float  f32x4;

typedef const __attribute__((address_space(1))) unsigned int* gas_u32p;
typedef __attribute__((address_space(3))) unsigned int*       las_u32p;

__device__ __forceinline__ void gld_lds16(const void* g, void* l) {
    __builtin_amdgcn_global_load_lds((gas_u32p)g, (las_u32p)l, 16, 0, 0);
}

__device__ __forceinline__ void bar() {
    __builtin_amdgcn_sched_barrier(0);
    __builtin_amdgcn_s_barrier();
    __builtin_amdgcn_sched_barrier(0);
}

// ---------------- k1: transpose (blocks < TBLK) + gather ----------------
__global__ __launch_bounds__(256) void prep_kernel(
    const float* __restrict__ W0, const float* __restrict__ W1,
    __hip_bfloat16* __restrict__ W0t, __hip_bfloat16* __restrict__ W1t,
    const int* __restrict__ feats, const float* __restrict__ values,
    const float* __restrict__ biasp, const float* __restrict__ weights,
    const float* __restrict__ embedding,
    float* __restrict__ fs, __hip_bfloat16* __restrict__ x)
{
    const int bid = blockIdx.x;
    if (bid < TBLK) {
        const int which = bid >= TB_W0;
        const int i  = which ? bid - TB_W0 : bid;
        const int nx = which ? 13 : 25;
        const int bx = i % nx, by = i / nx;
        const float* src = which ? W1 : W0;
        __hip_bfloat16* dst = which ? W1t : W0t;
        const int srcK = which ? HDIM : DDIM;
        const int dstCols = which ? HPAD : DDIM;

        __shared__ float tile[32][33];
        const int tx = threadIdx.x & 31, ty = threadIdx.x >> 5;
        const int k0 = bx * 32, n0 = by * 32;
#pragma unroll
        for (int r = 0; r < 4; ++r) {
            int k = k0 + ty + r * 8;
            int n = n0 + tx;
            float v = (k < srcK && n < HDIM) ? src[(long)k * HDIM + n] : 0.f;
            tile[ty + r * 8][tx] = v;
        }
        __syncthreads();
#pragma unroll
        for (int r = 0; r < 4; ++r) {
            int n = n0 + ty + r * 8;
            int k = k0 + tx;
            if (k < dstCols)
                dst[(long)n * dstCols + k] = __float2bfloat16(tile[tx][ty + r * 8]);
        }
        return;
    }

    const int wave = threadIdx.x >> 6;
    const int lane = threadIdx.x & 63;
    const int r    = lane >> 2, c = lane & 3;
    const int sbase = (bid - TBLK) * 16 + wave * 4;

    int   f[4] = {0, 0, 0, 0};
    float v[4] = {0.f, 0.f, 0.f, 0.f};
    float wsum[4] = {0.f, 0.f, 0.f, 0.f};
#pragma unroll
    for (int q = 0; q < 4; ++q) {
        const long base = (long)(sbase + q) * NFLD;
        if (lane < NFLD) {
            f[q] = feats[base + lane];
            v[q] = values[base + lane];
            wsum[q] = weights[f[q]] * v[q];
        }
    }

    int   fj[4][4]; float vj[4][4];
#pragma unroll
    for (int q = 0; q < 4; ++q)
#pragma unroll
        for (int p = 0; p < 4; ++p) {
            const int j = p * 16 + r;
            if (p < 3 || r < 2) {
                fj[q][p] = __shfl(f[q], j);
                vj[q][p] = __shfl(v[q], j);
            }
        }
    float4 e[4][4];
#pragma unroll
    for (int q = 0; q < 4; ++q)
#pragma unroll
        for (int p = 0; p < 4; ++p)
            if (p < 3 || r < 2)
                e[q][p] = *(const float4*)(embedding + (long)fj[q][p] * EK + c * 4);

#pragma unroll
    for (int q = 0; q < 4; ++q) {
        const int s = sbase + q;
        f32x4 s1 = {0.f, 0.f, 0.f, 0.f}, s2 = {0.f, 0.f, 0.f, 0.f};
#pragma unroll
        for (int p = 0; p < 4; ++p) {
            const int j = p * 16 + r;
            if (p < 3 || r < 2) {
                f32x4 ef = {e[q][p].x, e[q][p].y, e[q][p].z, e[q][p].w};
                f32x4 ev = ef * vj[q][p];
                s1 += ev;
                s2 += ev * ev;
                __hip_bfloat16 pk[4] = {
                    __float2bfloat16(e[q][p].x), __float2bfloat16(e[q][p].y),
                    __float2bfloat16(e[q][p].z), __float2bfloat16(e[q][p].w)};
                *(uint2*)&x[(long)s * DDIM + j * EK + c * 4] = *(uint2*)pk;
            }
        }
#pragma unroll
        for (int m = 4; m <= 32; m <<= 1) {
            s1.x += __shfl_xor(s1.x, m); s1.y += __shfl_xor(s1.y, m);
            s1.z += __shfl_xor(s1.z, m); s1.w += __shfl_xor(s1.w, m);
            s2.x += __shfl_xor(s2.x, m); s2.y += __shfl_xor(s2.y, m);
            s2.z += __shfl_xor(s2.z, m); s2.w += __shfl_xor(s2.w, m);
        }
        float t = (s1.x * s1.x - s2.x) + (s1.y * s1.y - s2.y)
                + (s1.z * s1.z - s2.z) + (s1.w * s1.w - s2.w);
        t += __shfl_xor(t, 1); t += __shfl_xor(t, 2);
        float w = wsum[q];
        w += __shfl_xor(w, 1);  w += __shfl_xor(w, 2);
        w += __shfl_xor(w, 4);  w += __shfl_xor(w, 8);
        w += __shfl_xor(w, 16); w += __shfl_xor(w, 32);
        if (lane == 0) fs[s] = w + 0.5f * t + biasp[0];
    }
}

// ---------------- k2: fused GEMM1 -> LDS h0 -> GEMM2 -> final ----------------
__global__ __launch_bounds__(512, 2) void fused_mlp_kernel(
    const __hip_bfloat16* __restrict__ x,
    const __hip_bfloat16* __restrict__ W0t, const __hip_bfloat16* __restrict__ W1t,
    const float* __restrict__ b0p, const float* __restrict__ b1p,
    const float* __restrict__ W2, const float* __restrict__ b2p,
    const float* __restrict__ fs, float* __restrict__ out)
{
    __shared__ __align__(16) char lds[LDSSZ];
    __hip_bfloat16* apan = (__hip_bfloat16*)lds;          // A panel, 100 KB
    __hip_bfloat16* h0p  = (__hip_bfloat16*)lds;          // overwrites A later
    float*          red  = (float*)(lds + REDOFF);

    const int tid  = threadIdx.x;
    const int wave = tid >> 6, lane = tid & 63;
    const int l16  = lane & 15, quad = lane >> 4;
    const int m0 = blockIdx.x * MROWS;
    const int nbase = wave * 64;                          // 1M x 8N

    // staging lane geometry (chunk = 16 rows x 32 cols = 1 KB)
    const int rl  = lane >> 2;
    const int swc = ((lane & 3) ^ ((lane >> 3) & 3)) * 8; // pre-swizzled src slot
    const int qsw = (quad ^ ((l16 >> 1) & 3)) * 8;        // swizzled read slot

    const float b0 = b0p[0];
    const float b1 = b1p[0];

    // ---- A panel preload: 100 chunks (plane = id>>2, rowgroup = id&3) ----
#pragma unroll
    for (int c = 0; c < 13; ++c) {
        const int id = c * 8 + wave;                      // wave-uniform
        if (id < 100)
            gld_lds16(x + (long)(m0 + (id & 3) * 16 + rl) * DDIM + (id >> 2) * 32 + swc,
                      lds + id * 1024 + lane * 16);
    }
    VMCNT(0);
    bar();

    // ---- phase 1: h0 = relu(x @ W0t + b0), 25 planes, no barriers ----
    f32x4 acc[4][4] = {};
    const __hip_bfloat16* bp1 = W0t + (long)(nbase + l16) * DDIM + quad * 8;

    auto loadB1 = [&](int p, bf16x8* bb) {
#pragma unroll
        for (int j = 0; j < 4; ++j)
            bb[j] = *(const bf16x8*)(bp1 + (long)j * 16 * DDIM + p * 32);
    };
    auto comp1 = [&](int p, const bf16x8* bb) {
        bf16x8 af[4];
#pragma unroll
        for (int i = 0; i < 4; ++i)
            af[i] = *(const bf16x8*)&apan[p * 2048 + i * 512 + l16 * 32 + qsw];
        __builtin_amdgcn_s_setprio(1);
#pragma unroll
        for (int i = 0; i < 4; ++i)
#pragma unroll
            for (int j = 0; j < 4; ++j)
                acc[i][j] = __builtin_amdgcn_mfma_f32_16x16x32_bf16(
                    af[i], bb[j], acc[i][j], 0, 0, 0);
        __builtin_amdgcn_s_setprio(0);
    };

    {
        bf16x8 bA[4], bB[4];
        loadB1(0, bA);
        loadB1(1, bB);
        for (int p = 0; p < P1 - 1; p += 2) {
            comp1(p, bA);
            if (p + 2 < P1) loadB1(p + 2, bA);
            comp1(p + 1, bB);
            if (p + 3 < P1) loadB1(p + 3, bB);
        }
        comp1(P1 - 1, bA);                                // plane 24
    }

    // phase-2 B prologue: issue early (regs only, no LDS hazard)
    const __hip_bfloat16* bp2 = W1t + (long)(nbase + l16) * HPAD + quad * 8;
    auto loadB2 = [&](int p, bf16x8* bb) {
#pragma unroll
        for (int j = 0; j < 4; ++j)
            bb[j] = *(const bf16x8*)(bp2 + (long)j * 16 * HPAD + p * 32);
    };
    bf16x8 cA[4], cB[4];
    loadB2(0, cA);
    loadB2(1, cB);

    bar();   // all waves done reading A panel -> safe to overwrite with h0p

    // ---- h0 -> LDS [64][H0S], relu+b0; cols >= HPAD skipped ----
#pragma unroll
    for (int i = 0; i < 4; ++i)
#pragma unroll
        for (int j = 0; j < 4; ++j) {
            const int col = nbase + j * 16 + l16;
            if (col < HPAD) {
#pragma unroll
                for (int r = 0; r < 4; ++r) {
                    const int row = i * 16 + quad * 4 + r;
                    float v = acc[i][j][r] + b0;
                    v = v > 0.f ? v : 0.f;
                    if (col >= HDIM) v = 0.f;
                    h0p[row * H0S + col] = __float2bfloat16(v);
                }
            }
        }
    asm volatile("s_waitcnt lgkmcnt(0)" ::: "memory");
    bar();   // h0p published (B prefetch still in flight)

    // ---- phase 2: relu(h0 @ W1t + b1) . W2, 13 planes, no barriers ----
    f32x4 acc2[4][4] = {};
    auto comp2 = [&](int p, const bf16x8* bb) {
        bf16x8 af[4];
#pragma unroll
        for (int i = 0; i < 4; ++i)
            af[i] = *(const bf16x8*)&h0p[(i * 16 + l16) * H0S + p * 32 + quad * 8];
        __builtin_amdgcn_s_setprio(1);
#pragma unroll
        for (int i = 0; i < 4; ++i)
#pragma unroll
            for (int j = 0; j < 4; ++j)
                acc2[i][j] = __builtin_amdgcn_mfma_f32_16x16x32_bf16(
                    af[i], bb[j], acc2[i][j], 0, 0, 0);
        __builtin_amdgcn_s_setprio(0);
    };

    for (int p = 0; p < P2 - 1; p += 2) {
        comp2(p, cA);
        if (p + 2 < P2) loadB2(p + 2, cA);
        comp2(p + 1, cB);
        if (p + 3 < P2) loadB2(p + 3, cB);
    }
    comp2(P2 - 1, cA);                                    // plane 12

    // ---- epilogue: relu(acc2+b1) . W2, lane reduce, cross-wave, sigmoid ----
    float w2v[4];
#pragma unroll
    for (int j = 0; j < 4; ++j) {
        const int col = nbase + j * 16 + l16;
        w2v[j] = (col < HDIM) ? W2[col] : 0.f;
    }
#pragma unroll
    for (int i = 0; i < 4; ++i)
#pragma unroll
        for (int r = 0; r < 4; ++r) {
            float ps = 0.f;
#pragma unroll
            for (int j = 0; j < 4; ++j) {
                float v = acc2[i][j][r] + b1;
                v = v > 0.f ? v : 0.f;
                ps += v * w2v[j];
            }
            ps += __shfl_xor(ps, 1); ps += __shfl_xor(ps, 2);
            ps += __shfl_xor(ps, 4); ps += __shfl_xor(ps, 8);
            if (l16 == 0)
                red[(i * 16 + quad * 4 + r) * 8 + wave] = ps;
        }
    __syncthreads();

    if (tid < MROWS) {
        const float4 r0 = *(const float4*)&red[tid * 8];
        const float4 r1 = *(const float4*)&red[tid * 8 + 4];
        const float s = ((r0.x + r0.y) + (r0.z + r0.w))
                      + ((r1.x + r1.y) + (r1.z + r1.w));
        float hv = s + b2p[0];
        hv = hv > 0.f ? hv : 0.f;
        const float z = fs[m0 + tid] + hv;
        out[m0 + tid] = 1.f / (1.f + __expf(-z));
    }
}

extern "C" void kernel_launch(void* const* d_in, const int* in_sizes, int n_in,
                              void* d_out, int out_size, void* d_ws, size_t ws_size,
                              hipStream_t stream)
{
    const int*   feats     = (const int*)d_in[1];
    const float* values    = (const float*)d_in[2];
    const float* bias      = (const float*)d_in[3];
    const float* weights   = (const float*)d_in[4];
    const float* embedding = (const float*)d_in[5];
    const float* W0 = (const float*)d_in[6];
    const float* b0 = (const float*)d_in[7];
    const float* W1 = (const float*)d_in[8];
    const float* b1 = (const float*)d_in[9];
    const float* W2 = (const float*)d_in[10];
    const float* b2 = (const float*)d_in[11];

    char* ws = (char*)d_ws;
    size_t off = 0;
    auto alloc = [&](size_t bytes) {
        void* p = ws + off;
        off += (bytes + 255) & ~(size_t)255;
        return p;
    };
    float*          fs   = (float*)alloc((size_t)BATCH * 4);
    __hip_bfloat16* x    = (__hip_bfloat16*)alloc((size_t)BATCH * DDIM * 2);
    __hip_bfloat16* W0t  = (__hip_bfloat16*)alloc((size_t)NPAD * DDIM * 2);
    __hip_bfloat16* W1t  = (__hip_bfloat16*)alloc((size_t)NPAD * HPAD * 2);
    (void)ws_size; (void)in_sizes; (void)n_in; (void)out_size;

    prep_kernel<<<dim3(TBLK + GBLK), 256, 0, stream>>>(
        W0, W1, W0t, W1t, feats, values, bias, weights, embedding, fs, x);
    fused_mlp_kernel<<<dim3(BATCH / MROWS), 512, 0, stream>>>(
        x, W0t, W1t, b0, b1, W2, b2, fs, (float*)d_out);
}

// Round 8
// 167.451 us; speedup vs baseline: 1.0224x; 1.0224x over previous
//
#include <hip/hip_runtime.h>
#include <hip/hip_bf16.h>

// DeepFM on MI355X. B=16384, NF=50, K=16, V=1e6, H=400, d=800.
// index = repeat(arange(B), NF) -> sample s owns rows [s*50, s*50+50).
//
// Timed-region decomposition: ~121us = 3x 256-MiB harness poison fills
// (fixed floor) + prep ~14us + fused (target; R6 = ~31us, R7 regressed).
//
// R7 post-mortem: direct-global B (no LDS) is latency-bound (L2 scatter
// loads, 2-plane reg lookahead, 2 waves/SIMD) -> reverted to R6's DMA
// staging + counted vmcnt.  R8 change: wave-tile geometry only.
//   R6: 8 waves 2Mx4N, per-wave 32x112 (Mf2+Nf7 = 9 ds_read_b128 / 14 MFMA)
//   R8: 7 waves 1Mx7N, per-wave 64x64  (Mf4+Nf4 = 8 ds_read_b128 / 16 MFMA)
//   -> per-CU LDS reads/plane 72 -> 56 (-22%) at identical MFMA count.
// Staging: 32 chunks/plane split 5/4 across 7 waves; uniform VMCNT(4) is
// safe (5-chunk waves over-wait one chunk of the NEXT plane).  Schedule,
// swizzle (rule #21 both-sides), setprio, 1-bar/plane, 3-deep buffers,
// phase-2 structure: all R6-identical.

#define BATCH 16384
#define NFLD  50
#define EK    16
#define DDIM  800   // NF*K  (= gemm1 K, exact, 25 planes)
#define HDIM  400
#define HPAD  416   // gemm2 K (13 planes)
#define NPAD  512   // W0t/W1t allocated rows

#define TB_W0 400            // 25 k-tiles x 16 n-tiles for W0 transpose
#define TB_W1 208            // 13 k-tiles x 16 n-tiles for W1 transpose
#define TBLK  (TB_W0 + TB_W1)
#define GBLK  (BATCH / 16)

#define MROWS 64             // samples per fused block
#define NCOLS 448            // gemm n-cols computed (28x16); 7 waves x 64
#define P1    (DDIM / 32)    // 25 K-planes, phase 1
#define P2    (HPAD / 32)    // 13 K-planes, phase 2
#define H0S   424            // h0 LDS stride: 848B rows -> 2-way af reads

// LDS byte offsets
#define PH1B(b) ((b) * 32768)          // 3 plane buffers (A 4KB + B 28KB)
#define PH2B(b) ((b) * 28672)          // 3 plane buffers (B only, 28KB)
#define H0OFF   98304                  // h0p: 64*424*2 = 54272 B
#define REDOFF  152576                 // red: 64*8*4 = 2048 B
#define LDSSZ   154624                 // 151 KB

#define VMCNT(N) asm volatile("s_waitcnt vmcnt(" #N ")" ::: "memory")

typedef __attribute__((ext_vector_type(8))) __bf16 bf16x8;
typedef __attribute__((ext_vector_type(4))) float  f32x4;

typedef const __attribute__((address_space(1))) unsigned int* gas_u32p;
typedef __attribute__((address_space(3))) unsigned int*       las_u32p;

__device__ __forceinline__ void gld_lds16(const void* g, void* l) {
    __builtin_amdgcn_global_load_lds((gas_u32p)g, (las_u32p)l, 16, 0, 0);
}

__device__ __forceinline__ void bar() {
    // raw barrier (no vmcnt drain) with compile-time fences (rule #18/#21)
    __builtin_amdgcn_sched_barrier(0);
    __builtin_amdgcn_s_barrier();
    __builtin_amdgcn_sched_barrier(0);
}

// ---------------- k1: transpose (blocks < TBLK) + gather ----------------
__global__ __launch_bounds__(256) void prep_kernel(
    const float* __restrict__ W0, const float* __restrict__ W1,
    __hip_bfloat16* __restrict__ W0t, __hip_bfloat16* __restrict__ W1t,
    const int* __restrict__ feats, const float* __restrict__ values,
    const float* __restrict__ biasp, const float* __restrict__ weights,
    const float* __restrict__ embedding,
    float* __restrict__ fs, __hip_bfloat16* __restrict__ x)
{
    const int bid = blockIdx.x;
    if (bid < TBLK) {
        const int which = bid >= TB_W0;
        const int i  = which ? bid - TB_W0 : bid;
        const int nx = which ? 13 : 25;                  // k-tiles
        const int bx = i % nx, by = i / nx;
        const float* src = which ? W1 : W0;
        __hip_bfloat16* dst = which ? W1t : W0t;
        const int srcK = which ? HDIM : DDIM;            // source rows (k)
        const int dstCols = which ? HPAD : DDIM;

        __shared__ float tile[32][33];
        const int tx = threadIdx.x & 31, ty = threadIdx.x >> 5;
        const int k0 = bx * 32, n0 = by * 32;
#pragma unroll
        for (int r = 0; r < 4; ++r) {
            int k = k0 + ty + r * 8;
            int n = n0 + tx;
            float v = (k < srcK && n < HDIM) ? src[(long)k * HDIM + n] : 0.f;
            tile[ty + r * 8][tx] = v;
        }
        __syncthreads();
#pragma unroll
        for (int r = 0; r < 4; ++r) {
            int n = n0 + ty + r * 8;   // dst row
            int k = k0 + tx;           // dst col
            if (k < dstCols)
                dst[(long)n * dstCols + k] = __float2bfloat16(tile[tx][ty + r * 8]);
        }
        return;
    }

    const int wave = threadIdx.x >> 6;
    const int lane = threadIdx.x & 63;
    const int r    = lane >> 2, c = lane & 3;
    const int sbase = (bid - TBLK) * 16 + wave * 4;

    int   f[4] = {0, 0, 0, 0};
    float v[4] = {0.f, 0.f, 0.f, 0.f};
    float wsum[4] = {0.f, 0.f, 0.f, 0.f};
#pragma unroll
    for (int q = 0; q < 4; ++q) {
        const long base = (long)(sbase + q) * NFLD;
        if (lane < NFLD) {
            f[q] = feats[base + lane];
            v[q] = values[base + lane];
            wsum[q] = weights[f[q]] * v[q];
        }
    }

    int   fj[4][4]; float vj[4][4];
#pragma unroll
    for (int q = 0; q < 4; ++q)
#pragma unroll
        for (int p = 0; p < 4; ++p) {
            const int j = p * 16 + r;
            if (p < 3 || r < 2) {
                fj[q][p] = __shfl(f[q], j);
                vj[q][p] = __shfl(v[q], j);
            }
        }
    float4 e[4][4];
#pragma unroll
    for (int q = 0; q < 4; ++q)
#pragma unroll
        for (int p = 0; p < 4; ++p)
            if (p < 3 || r < 2)
                e[q][p] = *(const float4*)(embedding + (long)fj[q][p] * EK + c * 4);

#pragma unroll
    for (int q = 0; q < 4; ++q) {
        const int s = sbase + q;
        f32x4 s1 = {0.f, 0.f, 0.f, 0.f}, s2 = {0.f, 0.f, 0.f, 0.f};
#pragma unroll
        for (int p = 0; p < 4; ++p) {
            const int j = p * 16 + r;
            if (p < 3 || r < 2) {
                f32x4 ef = {e[q][p].x, e[q][p].y, e[q][p].z, e[q][p].w};
                f32x4 ev = ef * vj[q][p];
                s1 += ev;
                s2 += ev * ev;
                __hip_bfloat16 pk[4] = {
                    __float2bfloat16(e[q][p].x), __float2bfloat16(e[q][p].y),
                    __float2bfloat16(e[q][p].z), __float2bfloat16(e[q][p].w)};
                *(uint2*)&x[(long)s * DDIM + j * EK + c * 4] = *(uint2*)pk;
            }
        }
#pragma unroll
        for (int m = 4; m <= 32; m <<= 1) {
            s1.x += __shfl_xor(s1.x, m); s1.y += __shfl_xor(s1.y, m);
            s1.z += __shfl_xor(s1.z, m); s1.w += __shfl_xor(s1.w, m);
            s2.x += __shfl_xor(s2.x, m); s2.y += __shfl_xor(s2.y, m);
            s2.z += __shfl_xor(s2.z, m); s2.w += __shfl_xor(s2.w, m);
        }
        float t = (s1.x * s1.x - s2.x) + (s1.y * s1.y - s2.y)
                + (s1.z * s1.z - s2.z) + (s1.w * s1.w - s2.w);
        t += __shfl_xor(t, 1); t += __shfl_xor(t, 2);
        float w = wsum[q];
        w += __shfl_xor(w, 1);  w += __shfl_xor(w, 2);
        w += __shfl_xor(w, 4);  w += __shfl_xor(w, 8);
        w += __shfl_xor(w, 16); w += __shfl_xor(w, 32);
        if (lane == 0) fs[s] = w + 0.5f * t + biasp[0];
    }
}

// ---------------- k2: fused GEMM1 -> LDS h0 -> GEMM2 -> final ----------------
// 7 waves (448 threads), 1M x 7N; per-wave tile 64 rows x 64 cols (4x4 frags).
__global__ __launch_bounds__(448) void fused_mlp_kernel(
    const __hip_bfloat16* __restrict__ x,
    const __hip_bfloat16* __restrict__ W0t, const __hip_bfloat16* __restrict__ W1t,
    const float* __restrict__ b0p, const float* __restrict__ b1p,
    const float* __restrict__ W2, const float* __restrict__ b2p,
    const float* __restrict__ fs, float* __restrict__ out)
{
    __shared__ __align__(16) char lds[LDSSZ];
    __hip_bfloat16* h0p = (__hip_bfloat16*)(lds + H0OFF);
    float*          red = (float*)(lds + REDOFF);

    const int tid  = threadIdx.x;
    const int wave = tid >> 6, lane = tid & 63;
    const int l16  = lane & 15, quad = lane >> 4;
    const int m0 = blockIdx.x * MROWS;
    const int nbase = wave * 64;                          // 7-way N split

    // staging lane geometry: chunk = 16 rows x 32 cols (1 KB);
    // lane -> row lane>>2, 16B slot lane&3; SOURCE slot pre-swizzled (rule #21)
    const int rl  = lane >> 2;
    const int swc = ((lane & 3) ^ ((lane >> 3) & 3)) * 8;   // = slot ^ ((row>>1)&3)
    // fragment-read slot swizzle: logical slot `quad` lives at quad ^ ((l16>>1)&3)
    const int qsw = (quad ^ ((l16 >> 1) & 3)) * 8;

    const float b0 = b0p[0];
    const float b1 = b1p[0];

    // ---- phase-1 staging: 1 plane = 32 chunks (A: 0..3 x-rows, B: 4..31
    // W0t rows); waves 0..3 stage 5 chunks, waves 4..6 stage 4 ----
    const int sstart = (wave < 4) ? wave * 5 : 20 + (wave - 4) * 4;
    const int scnt   = (wave < 4) ? 5 : 4;
    auto stage1 = [&](int p, int b) {
        const int k0 = p * 32;
        char* dst = lds + PH1B(b);
#pragma unroll
        for (int c = 0; c < 5; ++c) {
            if (c < scnt) {                          // wave-uniform guard
                const int id = sstart + c;
                const __hip_bfloat16* src = (id < 4)
                    ? x   + (long)(m0 + id * 16 + rl) * DDIM + k0 + swc
                    : W0t + (long)((id - 4) * 16 + rl) * DDIM + k0 + swc;
                gld_lds16(src, dst + id * 1024 + lane * 16);
            }
        }
    };

    f32x4 acc[4][4] = {};
    auto compute1 = [&](int b) {
        const __hip_bfloat16* s = (const __hip_bfloat16*)(lds + PH1B(b));
        bf16x8 af[4], bfr[4];
#pragma unroll
        for (int i = 0; i < 4; ++i)
            af[i] = *(const bf16x8*)&s[i * 512 + l16 * 32 + qsw];
#pragma unroll
        for (int j = 0; j < 4; ++j)
            bfr[j] = *(const bf16x8*)&s[(4 + wave * 4 + j) * 512 + l16 * 32 + qsw];
        __builtin_amdgcn_s_setprio(1);
#pragma unroll
        for (int i = 0; i < 4; ++i)
#pragma unroll
            for (int j = 0; j < 4; ++j)
                acc[i][j] = __builtin_amdgcn_mfma_f32_16x16x32_bf16(
                    af[i], bfr[j], acc[i][j], 0, 0, 0);
        __builtin_amdgcn_s_setprio(0);
    };

    // ---- phase 1: 25 planes, 3-deep, ONE barrier per plane ----
    // VMCNT(4): plane p landed for 4-chunk waves; 5-chunk waves over-wait
    // one chunk of plane p+1 (safe).  stage(p+2) after bar(p) is race-free.
    stage1(0, 0);
    stage1(1, 1);
    for (int p = 0; p < P1; ++p) {
        if (p + 1 < P1) { VMCNT(4); } else { VMCNT(0); }
        bar();
        if (p + 2 < P1) stage1(p + 2, (p + 2) % 3);
        compute1(p % 3);
    }
    bar();   // all compute1 ds_reads done before phase-2 staging overwrites

    // prologue for phase 2: issue planes 0,1 ASAP (overlap with h0p writes)
    auto stage2 = [&](int p, int b) {
        const int k0 = p * 32;
#pragma unroll
        for (int c = 0; c < 4; ++c) {
            const int ch = wave * 4 + c;             // 0..27, wave-uniform
            gld_lds16(W1t + (long)(ch * 16 + rl) * HPAD + k0 + swc,
                      lds + PH2B(b) + ch * 1024 + lane * 16);
        }
    };
    stage2(0, 0);
    stage2(1, 1);

    // ---- h0 panel -> LDS, relu+b0; cols [400,416)->0; >=416 dropped ----
#pragma unroll
    for (int i = 0; i < 4; ++i)
#pragma unroll
        for (int j = 0; j < 4; ++j) {
            const int col = nbase + j * 16 + l16;
            if (col < HPAD) {
#pragma unroll
                for (int r = 0; r < 4; ++r) {
                    const int row = i * 16 + quad * 4 + r;
                    float v = acc[i][j][r] + b0;
                    v = v > 0.f ? v : 0.f;
                    if (col >= HDIM) v = 0.f;
                    h0p[row * H0S + col] = __float2bfloat16(v);
                }
            }
        }

    f32x4 acc2[4][4] = {};
    float w2v[4];
#pragma unroll
    for (int j = 0; j < 4; ++j) {
        const int col = nbase + j * 16 + l16;
        w2v[j] = (col < HDIM) ? W2[col] : 0.f;
    }
    auto compute2 = [&](int p, int b) {
        const __hip_bfloat16* s = (const __hip_bfloat16*)(lds + PH2B(b));
        bf16x8 af[4], bfr[4];
#pragma unroll
        for (int i = 0; i < 4; ++i)
            af[i] = *(const bf16x8*)&h0p[(i * 16 + l16) * H0S + p * 32 + quad * 8];
#pragma unroll
        for (int j = 0; j < 4; ++j)
            bfr[j] = *(const bf16x8*)&s[(wave * 4 + j) * 512 + l16 * 32 + qsw];
        __builtin_amdgcn_s_setprio(1);
#pragma unroll
        for (int i = 0; i < 4; ++i)
#pragma unroll
            for (int j = 0; j < 4; ++j)
                acc2[i][j] = __builtin_amdgcn_mfma_f32_16x16x32_bf16(
                    af[i], bfr[j], acc2[i][j], 0, 0, 0);
        __builtin_amdgcn_s_setprio(0);
    };

    // publish h0p (ds_writes) WITHOUT draining the in-flight stage2 DMA
    asm volatile("s_waitcnt lgkmcnt(0)" ::: "memory");
    bar();

    // ---- phase 2: 13 planes, 3-deep, ONE barrier per plane ----
    for (int p = 0; p < P2; ++p) {
        if (p + 1 < P2) { VMCNT(4); } else { VMCNT(0); }
        bar();
        if (p + 2 < P2) stage2(p + 2, (p + 2) % 3);
        compute2(p, p % 3);
    }

    // ---- epilogue: relu(acc2+b1) . W2, lane reduce, cross-wave, sigmoid ----
    if (tid < MROWS) red[tid * 8 + 7] = 0.f;             // pad col (7 waves)
#pragma unroll
    for (int i = 0; i < 4; ++i)
#pragma unroll
        for (int r = 0; r < 4; ++r) {
            float ps = 0.f;
#pragma unroll
            for (int j = 0; j < 4; ++j) {
                float v = acc2[i][j][r] + b1;
                v = v > 0.f ? v : 0.f;
                ps += v * w2v[j];
            }
            ps += __shfl_xor(ps, 1); ps += __shfl_xor(ps, 2);
            ps += __shfl_xor(ps, 4); ps += __shfl_xor(ps, 8);
            if (l16 == 0)
                red[(i * 16 + quad * 4 + r) * 8 + wave] = ps;
        }
    __syncthreads();

    if (tid < MROWS) {
        const float4 r0 = *(const float4*)&red[tid * 8];
        const float4 r1 = *(const float4*)&red[tid * 8 + 4];
        const float s = ((r0.x + r0.y) + (r0.z + r0.w))
                      + ((r1.x + r1.y) + (r1.z + r1.w));
        float hv = s + b2p[0];
        hv = hv > 0.f ? hv : 0.f;
        const float z = fs[m0 + tid] + hv;
        out[m0 + tid] = 1.f / (1.f + __expf(-z));
    }
}

extern "C" void kernel_launch(void* const* d_in, const int* in_sizes, int n_in,
                              void* d_out, int out_size, void* d_ws, size_t ws_size,
                              hipStream_t stream)
{
    const int*   feats     = (const int*)d_in[1];
    const float* values    = (const float*)d_in[2];
    const float* bias      = (const float*)d_in[3];
    const float* weights   = (const float*)d_in[4];
    const float* embedding = (const float*)d_in[5];
    const float* W0 = (const float*)d_in[6];
    const float* b0 = (const float*)d_in[7];
    const float* W1 = (const float*)d_in[8];
    const float* b1 = (const float*)d_in[9];
    const float* W2 = (const float*)d_in[10];
    const float* b2 = (const float*)d_in[11];

    char* ws = (char*)d_ws;
    size_t off = 0;
    auto alloc = [&](size_t bytes) {
        void* p = ws + off;
        off += (bytes + 255) & ~(size_t)255;
        return p;
    };
    float*          fs   = (float*)alloc((size_t)BATCH * 4);
    __hip_bfloat16* x    = (__hip_bfloat16*)alloc((size_t)BATCH * DDIM * 2);
    __hip_bfloat16* W0t  = (__hip_bfloat16*)alloc((size_t)NPAD * DDIM * 2);
    __hip_bfloat16* W1t  = (__hip_bfloat16*)alloc((size_t)NPAD * HPAD * 2);
    (void)ws_size; (void)in_sizes; (void)n_in; (void)out_size;

    prep_kernel<<<dim3(TBLK + GBLK), 256, 0, stream>>>(
        W0, W1, W0t, W1t, feats, values, bias, weights, embedding, fs, x);
    fused_mlp_kernel<<<dim3(BATCH / MROWS), 448, 0, stream>>>(
        x, W0t, W1t, b0, b1, W2, b2, fs, (float*)d_out);
}